// Round 22
// baseline (242.256 us; speedup 1.0000x reference)
//
#include <hip/hip_runtime.h>

#define S_LEN 2048
#define DMODEL 1024
#define NH 16
#define NKVH 4
#define DKH 64
#define KVD 256
#define SCALE_LOG2E 0.18033688f  // (1/sqrt(64)) * log2(e)

typedef __bf16 bf16;
typedef bf16  bf16x8 __attribute__((ext_vector_type(8)));
typedef bf16  bf16x4 __attribute__((ext_vector_type(4)));
typedef float f32x4  __attribute__((ext_vector_type(4)));
typedef bf16x8 bf16x8_a __attribute__((may_alias));
typedef bf16x4 bf16x4_a __attribute__((may_alias));
typedef float f32x4g __attribute__((ext_vector_type(4), may_alias));

#define VWAIT(N)                                             \
    do {                                                     \
        asm volatile("s_waitcnt vmcnt(" #N ")" ::: "memory");\
        __builtin_amdgcn_sched_barrier(0);                   \
    } while (0)

__device__ __forceinline__ void gll16(const bf16* g, bf16* l) {
    __builtin_amdgcn_global_load_lds(
        (const __attribute__((address_space(1))) void*)g,
        (__attribute__((address_space(3))) void*)l, 16, 0, 0);
}

// ---------------- fused fp32 -> bf16 casts ----------------
__global__ __launch_bounds__(256) void cast3_bf16(const float* __restrict__ a,
                                                  const float* __restrict__ b,
                                                  const float* __restrict__ c,
                                                  bf16* __restrict__ oa, bf16* __restrict__ ob,
                                                  bf16* __restrict__ oc, int n4) {
    const float* src = blockIdx.y == 0 ? a : blockIdx.y == 1 ? b : c;
    bf16* dst = blockIdx.y == 0 ? oa : blockIdx.y == 1 ? ob : oc;
    int stride = gridDim.x * blockDim.x;
    for (int i = blockIdx.x * blockDim.x + threadIdx.x; i < n4; i += stride) {
        f32x4g v = ((const f32x4g*)src)[i];
        bf16x4 o;
        o[0] = (bf16)v[0]; o[1] = (bf16)v[1]; o[2] = (bf16)v[2]; o[3] = (bf16)v[3];
        ((bf16x4*)dst)[i] = o;
    }
}

__global__ __launch_bounds__(256) void cast4_bf16(const float* __restrict__ a,
                                                  const float* __restrict__ b,
                                                  const float* __restrict__ c,
                                                  const float* __restrict__ d,
                                                  bf16* __restrict__ oa, bf16* __restrict__ ob,
                                                  bf16* __restrict__ oc, bf16* __restrict__ od,
                                                  int n4big, int n4small) {
    const int y = blockIdx.y;
    const float* src = y == 0 ? a : y == 1 ? b : y == 2 ? c : d;
    bf16* dst = y == 0 ? oa : y == 1 ? ob : y == 2 ? oc : od;
    const int n4 = y < 2 ? n4big : n4small;
    int stride = gridDim.x * blockDim.x;
    for (int i = blockIdx.x * blockDim.x + threadIdx.x; i < n4; i += stride) {
        f32x4g v = ((const f32x4g*)src)[i];
        bf16x4 o;
        o[0] = (bf16)v[0]; o[1] = (bf16)v[1]; o[2] = (bf16)v[2]; o[3] = (bf16)v[3];
        ((bf16x4*)dst)[i] = o;
    }
}

// ---------------- NT GEMM core (128x128 tile, BK=32, 4 waves) ----------------
template <int OUTF32>
__device__ __forceinline__ void gemm_body(const bf16* __restrict__ A,
                                          const bf16* __restrict__ Bw,
                                          const float* __restrict__ bias,
                                          void* __restrict__ Cout, int bm, int bn, int N,
                                          int K, bf16* As, bf16* Bs) {
    const int tid = threadIdx.x, wave = tid >> 6, lane = tid & 63;
    const int l15 = lane & 15, lhi = lane >> 4;
    const int wr = (wave >> 1) * 64, wc = (wave & 1) * 64;
    f32x4 acc[4][4] = {};
    const size_t arow0 = (size_t)bm * 128 * K;
    const size_t brow0 = (size_t)bn * 128 * K;

    for (int kt = 0; kt < K; kt += 32) {
#pragma unroll
        for (int i = 0; i < 2; ++i) {
            int base = i * 2048 + wave * 512;
            int flat = base + lane * 8;
            int r = flat >> 5, c = flat & 31;
            gll16(A + arow0 + (size_t)r * K + kt + c, &As[base]);
            gll16(Bw + brow0 + (size_t)r * K + kt + c, &Bs[base]);
        }
        __syncthreads();
        bf16x8 af[4], bfr[4];
#pragma unroll
        for (int mi = 0; mi < 4; ++mi)
            af[mi] = *(const bf16x8_a*)&As[(wr + mi * 16 + l15) * 32 + lhi * 8];
#pragma unroll
        for (int ni = 0; ni < 4; ++ni)
            bfr[ni] = *(const bf16x8_a*)&Bs[(wc + ni * 16 + l15) * 32 + lhi * 8];
#pragma unroll
        for (int mi = 0; mi < 4; ++mi)
#pragma unroll
            for (int ni = 0; ni < 4; ++ni)
                acc[mi][ni] = __builtin_amdgcn_mfma_f32_16x16x32_bf16(
                    af[mi], bfr[ni], acc[mi][ni], 0, 0, 0);
        __syncthreads();
    }
#pragma unroll
    for (int mi = 0; mi < 4; ++mi)
#pragma unroll
        for (int ni = 0; ni < 4; ++ni)
#pragma unroll
            for (int j = 0; j < 4; ++j) {
                int row = bm * 128 + wr + mi * 16 + lhi * 4 + j;
                int col = bn * 128 + wc + ni * 16 + l15;
                float v = acc[mi][ni][j] + bias[col];
                if (OUTF32)
                    ((float*)Cout)[(size_t)row * N + col] = v;
                else
                    ((bf16*)Cout)[(size_t)row * N + col] = (bf16)v;
            }
}

template <int OUTF32>
__global__ __launch_bounds__(256) void gemm_bt(const bf16* __restrict__ A,
                                               const bf16* __restrict__ Bw,
                                               const float* __restrict__ bias,
                                               void* __restrict__ Cout,
                                               int M, int N, int K) {
    __shared__ bf16 As[4096];
    __shared__ bf16 Bs[4096];
    gemm_body<OUTF32>(A, Bw, bias, Cout, blockIdx.x, blockIdx.y, N, K, As, Bs);
}

// merged Q/K/V projection: grid (32, 12); by<8 -> Q, 8..9 -> K, 10..11 -> V
__global__ __launch_bounds__(256) void gemm_qkv(const bf16* __restrict__ qx,
                                                const bf16* __restrict__ kx,
                                                const bf16* __restrict__ vx,
                                                const bf16* __restrict__ wqx,
                                                const bf16* __restrict__ wkx,
                                                const bf16* __restrict__ wvx,
                                                const float* __restrict__ bq,
                                                const float* __restrict__ bk,
                                                const float* __restrict__ bv,
                                                bf16* __restrict__ Qp, bf16* __restrict__ Kp,
                                                bf16* __restrict__ Vp) {
    __shared__ bf16 As[4096];
    __shared__ bf16 Bs[4096];
    const int by = blockIdx.y;
    const bf16* A;
    const bf16* Bw;
    const float* bias;
    bf16* C;
    int N, bn;
    if (by < 8) {
        A = qx; Bw = wqx; bias = bq; C = Qp; N = 1024; bn = by;
    } else if (by < 10) {
        A = kx; Bw = wkx; bias = bk; C = Kp; N = 256; bn = by - 8;
    } else {
        A = vx; Bw = wvx; bias = bv; C = Vp; N = 256; bn = by - 10;
    }
    gemm_body<0>(A, Bw, bias, C, blockIdx.x, bn, N, 1024, As, Bs);
}

// ---------------- V transpose: Vp[b*2048+s][g*64+d] -> VT[b][g][d][s] ----------------
__global__ __launch_bounds__(256) void vtrans(const bf16* __restrict__ V,
                                              bf16* __restrict__ VT) {
    __shared__ bf16 t[64][65];
    const int s0 = blockIdx.x * 64;
    const int bg = blockIdx.y;
    const int b = bg >> 2, g = bg & 3;
#pragma unroll
    for (int i = 0; i < 16; ++i) {
        int flat = threadIdx.x + i * 256;
        int r = flat >> 6, c = flat & 63;
        t[c][r] = V[(size_t)(b * S_LEN + s0 + r) * KVD + g * DKH + c];
    }
    __syncthreads();
#pragma unroll
    for (int i = 0; i < 16; ++i) {
        int flat = threadIdx.x + i * 256;
        int d = flat >> 6, si = flat & 63;
        VT[((size_t)bg * DKH + d) * S_LEN + s0 + si] = t[d][si];
    }
}

// ---------------- merged attention v11: 16-phase pass A (ring-4 of pairs, depth-2) ----------------
// grid 512 (XCD-swizzled) = bh(32) x qt(16: 128 q-rows); block 512 = 8 waves x 16 q-rows.
// Pass A: 16 phases x 128 keys; pair p -> {KV[2(p&3)], KV[2(p&3)+1]}; stage pair(c+2) at
// iter c (2-phase lead). Pass B: K ring-4 KV[0..3] + V ring-4 KV[4..7], depth-2 (as R21).
__global__ __launch_bounds__(512, 4) void attn_all(const bf16* __restrict__ Qp,
                                                   const bf16* __restrict__ Kp,
                                                   const bf16* __restrict__ VT,
                                                   float* __restrict__ attn_out,
                                                   bf16* __restrict__ ctx) {
    __shared__ bf16 KV[8][4096];  // 64 KB
    __shared__ bf16 Pw[8][1024];  // 16 KB: per-wave [16 q][64 k] bf16, XOR-swizzled
    const int raw = blockIdx.x;
    const int wg = (raw & 7) * 64 + (raw >> 3);  // 512 % 8 == 0: bijective
    const int bh = wg >> 4;
    const int qt = wg & 15;
    const int h = bh & (NH - 1), b = bh >> 4, g = h >> 2;
    const int tid = threadIdx.x, wave = tid >> 6, lane = tid & 63;
    const int l15 = lane & 15, lhi = lane >> 4;
    const int qw = qt * 128 + wave * 16;
    const int sw = (l15 & 7) << 4;

    const bf16* qb = Qp + (size_t)(b * S_LEN + qw + l15) * DMODEL + h * DKH + lhi * 8;
    bf16x8 aq0 = *(const bf16x8_a*)qb;
    bf16x8 aq1 = *(const bf16x8_a*)(qb + 32);

    const int srow = tid >> 3;
    const int scc = (tid & 7) ^ (srow & 7);
    const bf16* ksrc = Kp + (size_t)(b * S_LEN + srow) * KVD + g * DKH + scc * 8;
    const bf16* vsrc = VT + ((size_t)(b * NKVH + g) * DKH + srow) * S_LEN + scc * 8;

    // ======== pass A: 16 phases x 128 keys; ring-4 of buffer-pairs, depth-2 ========
    // pair p -> KV[2*(p&3)], KV[2*(p&3)+1]
    gll16(ksrc, &KV[0][wave * 512]);
    gll16(ksrc + (size_t)64 * KVD, &KV[1][wave * 512]);
    gll16(ksrc + (size_t)128 * KVD, &KV[2][wave * 512]);
    gll16(ksrc + (size_t)192 * KVD, &KV[3][wave * 512]);
    float lsum = 0.f;
    for (int c = 0; c < 16; ++c) {
        if (c < 15) { VWAIT(2); } else { VWAIT(0); }  // pair(c) resident
        __builtin_amdgcn_s_barrier();
        if (c < 14) {
            const bf16* s = ksrc + (size_t)((c + 2) * 128) * KVD;
            const int bb = 2 * ((c + 2) & 3);
            gll16(s, &KV[bb][wave * 512]);
            gll16(s + (size_t)64 * KVD, &KV[bb + 1][wave * 512]);
        }
        const char* kcl = (const char*)&KV[2 * (c & 3)][0];
        const char* kch = (const char*)&KV[2 * (c & 3) + 1][0];
        __builtin_amdgcn_s_setprio(1);
#pragma unroll
        for (int s8 = 0; s8 < 8; ++s8) {
            const char* base = s8 < 4 ? kcl : kch;
            const int rb = ((s8 & 3) * 16 + l15) * 128;
            bf16x8 k0 = *(const bf16x8_a*)(base + rb + ((lhi * 16) ^ sw));
            bf16x8 k1 = *(const bf16x8_a*)(base + rb + ((lhi * 16 + 64) ^ sw));
            f32x4 a = {0.f, 0.f, 0.f, 0.f};
            a = __builtin_amdgcn_mfma_f32_16x16x32_bf16(k0, aq0, a, 0, 0, 0);
            a = __builtin_amdgcn_mfma_f32_16x16x32_bf16(k1, aq1, a, 0, 0, 0);
            lsum += __builtin_exp2f(a[0] * SCALE_LOG2E) + __builtin_exp2f(a[1] * SCALE_LOG2E) +
                    __builtin_exp2f(a[2] * SCALE_LOG2E) + __builtin_exp2f(a[3] * SCALE_LOG2E);
        }
        __builtin_amdgcn_s_setprio(0);
    }
    lsum += __shfl_xor(lsum, 16, 64);
    lsum += __shfl_xor(lsum, 32, 64);
    const float nlog = -__builtin_log2f(lsum);

    // pass-B prologue: stage(0) -> KV[0],KV[4]; stage(1) -> KV[1],KV[5].
    // Races: KV[0],KV[1] last read compute(12) [fenced by c=13 barrier]; KV[4],KV[5]
    // last read compute(14) [fenced by c=15 barrier]. Safe.
    gll16(ksrc, &KV[0][wave * 512]);
    gll16(vsrc, &KV[4][wave * 512]);
    gll16(ksrc + (size_t)64 * KVD, &KV[1][wave * 512]);
    gll16(vsrc + 64, &KV[5][wave * 512]);

    // ================= pass B: probs + PV (K,V ring-4, depth-2; P wave-private) =========
    f32x4 cacc[4] = {};
    char* pl = (char*)&Pw[wave][0] + l15 * 128;
    char* pls = (char*)&Pw[wave][0];
    const int stslot = lane & 15;
    const int strow4 = lane >> 4;
    float* gstb = attn_out + ((size_t)bh * S_LEN + qw) * S_LEN;

    for (int c = 0; c < 32; ++c) {
        if (c == 0) { VWAIT(2); }
        else if (c == 1) { VWAIT(6); }
        else if (c <= 30) { VWAIT(10); }
        else { VWAIT(8); }
        __builtin_amdgcn_s_barrier();  // stage(c) resident for all waves
        if (c < 30) {
            gll16(ksrc + (size_t)((c + 2) * 64) * KVD, &KV[(c + 2) & 3][wave * 512]);
            gll16(vsrc + (c + 2) * 64, &KV[4 + ((c + 2) & 3)][wave * 512]);
            __builtin_amdgcn_sched_barrier(0);  // stores must stay AFTER the gll16s
        }
        const char* kc = (const char*)&KV[c & 3][0];
        f32x4 a0 = {0.f, 0.f, 0.f, 0.f}, a1 = a0, a2 = a0, a3 = a0;
        __builtin_amdgcn_s_setprio(1);
        {
            const int rb = l15 * 128;
            bf16x8 k0 = *(const bf16x8_a*)(kc + rb + ((lhi * 16) ^ sw));
            bf16x8 k1 = *(const bf16x8_a*)(kc + rb + ((lhi * 16 + 64) ^ sw));
            a0 = __builtin_amdgcn_mfma_f32_16x16x32_bf16(k0, aq0, a0, 0, 0, 0);
            a0 = __builtin_amdgcn_mfma_f32_16x16x32_bf16(k1, aq1, a0, 0, 0, 0);
        }
        {
            const int rb = (16 + l15) * 128;
            bf16x8 k0 = *(const bf16x8_a*)(kc + rb + ((lhi * 16) ^ sw));
            bf16x8 k1 = *(const bf16x8_a*)(kc + rb + ((lhi * 16 + 64) ^ sw));
            a1 = __builtin_amdgcn_mfma_f32_16x16x32_bf16(k0, aq0, a1, 0, 0, 0);
            a1 = __builtin_amdgcn_mfma_f32_16x16x32_bf16(k1, aq1, a1, 0, 0, 0);
        }
        {
            const int rb = (32 + l15) * 128;
            bf16x8 k0 = *(const bf16x8_a*)(kc + rb + ((lhi * 16) ^ sw));
            bf16x8 k1 = *(const bf16x8_a*)(kc + rb + ((lhi * 16 + 64) ^ sw));
            a2 = __builtin_amdgcn_mfma_f32_16x16x32_bf16(k0, aq0, a2, 0, 0, 0);
            a2 = __builtin_amdgcn_mfma_f32_16x16x32_bf16(k1, aq1, a2, 0, 0, 0);
        }
        {
            const int rb = (48 + l15) * 128;
            bf16x8 k0 = *(const bf16x8_a*)(kc + rb + ((lhi * 16) ^ sw));
            bf16x8 k1 = *(const bf16x8_a*)(kc + rb + ((lhi * 16 + 64) ^ sw));
            a3 = __builtin_amdgcn_mfma_f32_16x16x32_bf16(k0, aq0, a3, 0, 0, 0);
            a3 = __builtin_amdgcn_mfma_f32_16x16x32_bf16(k1, aq1, a3, 0, 0, 0);
        }
        __builtin_amdgcn_s_setprio(0);
        {
            bf16x4 p0, p1, p2, p3;
#pragma unroll
            for (int j = 0; j < 4; ++j) {
                p0[j] = (bf16)__builtin_exp2f(__builtin_fmaf(a0[j], SCALE_LOG2E, nlog));
                p1[j] = (bf16)__builtin_exp2f(__builtin_fmaf(a1[j], SCALE_LOG2E, nlog));
                p2[j] = (bf16)__builtin_exp2f(__builtin_fmaf(a2[j], SCALE_LOG2E, nlog));
                p3[j] = (bf16)__builtin_exp2f(__builtin_fmaf(a3[j], SCALE_LOG2E, nlog));
            }
            *(bf16x4_a*)(pl + ((0 * 32 + lhi * 8) ^ sw)) = p0;
            *(bf16x4_a*)(pl + ((1 * 32 + lhi * 8) ^ sw)) = p1;
            *(bf16x4_a*)(pl + ((2 * 32 + lhi * 8) ^ sw)) = p2;
            *(bf16x4_a*)(pl + ((3 * 32 + lhi * 8) ^ sw)) = p3;
        }
        bf16x8 ap0 = *(const bf16x8_a*)(pl + ((lhi * 16) ^ sw));
        bf16x8 ap1 = *(const bf16x8_a*)(pl + ((lhi * 16 + 64) ^ sw));
        const char* vc = (const char*)&KV[4 + (c & 3)][0];
        __builtin_amdgcn_s_setprio(1);
#pragma unroll
        for (int t = 0; t < 4; ++t) {
            const int vb = (t * 16 + l15) * 128;
            bf16x8 v0 = *(const bf16x8_a*)(vc + vb + ((lhi * 16) ^ sw));
            bf16x8 v1 = *(const bf16x8_a*)(vc + vb + ((lhi * 16 + 64) ^ sw));
            cacc[t] = __builtin_amdgcn_mfma_f32_16x16x32_bf16(ap0, v0, cacc[t], 0, 0, 0);
            cacc[t] = __builtin_amdgcn_mfma_f32_16x16x32_bf16(ap1, v1, cacc[t], 0, 0, 0);
        }
        __builtin_amdgcn_s_setprio(0);
#pragma unroll
        for (int t = 0; t < 4; ++t) {
            const int r = t * 4 + strow4;
            bf16x4 pv4 =
                *(const bf16x4_a*)(pls + r * 128 + ((stslot * 8) ^ ((r & 7) << 4)));
            f32x4 pf4;
#pragma unroll
            for (int j = 0; j < 4; ++j) pf4[j] = (float)pv4[j];
            *(f32x4g*)(gstb + (size_t)r * S_LEN + c * 64 + stslot * 4) = pf4;
        }
    }
#pragma unroll
    for (int t = 0; t < 4; ++t)
#pragma unroll
        for (int j = 0; j < 4; ++j) {
            int row = qw + lhi * 4 + j;
            ctx[(size_t)(b * S_LEN + row) * DMODEL + h * DKH + t * 16 + l15] =
                (bf16)cacc[t][j];
        }
}

extern "C" void kernel_launch(void* const* d_in, const int* in_sizes, int n_in,
                              void* d_out, int out_size, void* d_ws, size_t ws_size,
                              hipStream_t stream) {
    const float* query = (const float*)d_in[0];
    const float* key_i = (const float*)d_in[1];
    const float* value = (const float*)d_in[2];
    const float* Wq = (const float*)d_in[3];
    const float* bq = (const float*)d_in[4];
    const float* Wk = (const float*)d_in[5];
    const float* bk = (const float*)d_in[6];
    const float* Wv = (const float*)d_in[7];
    const float* bv = (const float*)d_in[8];
    const float* Wo = (const float*)d_in[9];
    const float* bo = (const float*)d_in[10];

    char* ws = (char*)d_ws;
    bf16* qx = (bf16*)(ws + 0);
    bf16* kx = (bf16*)(ws + ((size_t)8 << 20));
    bf16* vx = (bf16*)(ws + ((size_t)16 << 20));
    bf16* wqx = (bf16*)(ws + ((size_t)32 << 20));
    bf16* wkx = (bf16*)(ws + ((size_t)34 << 20));
    bf16* wvx = (bf16*)(ws + ((size_t)34 << 20) + ((size_t)512 << 10));
    bf16* wox = (bf16*)(ws + ((size_t)35 << 20));
    bf16* Qp = (bf16*)(ws + ((size_t)37 << 20));
    bf16* Kp = (bf16*)(ws + ((size_t)45 << 20));
    bf16* Vp = (bf16*)(ws + ((size_t)47 << 20));
    bf16* VT = (bf16*)(ws + ((size_t)49 << 20));
    bf16* ctxb = (bf16*)(ws + ((size_t)51 << 20));

    const int BS = 2 * S_LEN;  // 4096 rows

    cast3_bf16<<<dim3(1024, 3), 256, 0, stream>>>(query, key_i, value, qx, kx, vx,
                                                  BS * DMODEL / 4);
    cast4_bf16<<<dim3(1024, 4), 256, 0, stream>>>(Wq, Wo, Wk, Wv, wqx, wox, wkx, wvx,
                                                  DMODEL * DMODEL / 4, KVD * DMODEL / 4);

    gemm_qkv<<<dim3(32, 12), 256, 0, stream>>>(qx, kx, vx, wqx, wkx, wvx, bq, bk, bv, Qp, Kp,
                                               Vp);

    vtrans<<<dim3(32, 8), 256, 0, stream>>>(Vp, VT);

    float* attn_out = (float*)d_out + (size_t)BS * DMODEL;
    attn_all<<<512, 512, 0, stream>>>(Qp, Kp, VT, attn_out, ctxb);

    gemm_bt<1><<<dim3(32, 8), 256, 0, stream>>>(ctxb, wox, bo, (float*)d_out, BS, DMODEL, DMODEL);
}

// Round 23
// 236.154 us; speedup vs baseline: 1.0258x; 1.0258x over previous
//
#include <hip/hip_runtime.h>

#define S_LEN 2048
#define DMODEL 1024
#define NH 16
#define NKVH 4
#define DKH 64
#define KVD 256
#define SCALE_LOG2E 0.18033688f  // (1/sqrt(64)) * log2(e)

typedef __bf16 bf16;
typedef bf16  bf16x8 __attribute__((ext_vector_type(8)));
typedef bf16  bf16x4 __attribute__((ext_vector_type(4)));
typedef float f32x4  __attribute__((ext_vector_type(4)));
typedef bf16x8 bf16x8_a __attribute__((may_alias));
typedef bf16x4 bf16x4_a __attribute__((may_alias));
typedef float f32x4g __attribute__((ext_vector_type(4), may_alias));

#define VWAIT(N)                                             \
    do {                                                     \
        asm volatile("s_waitcnt vmcnt(" #N ")" ::: "memory");\
        __builtin_amdgcn_sched_barrier(0);                   \
    } while (0)

__device__ __forceinline__ void gll16(const bf16* g, bf16* l) {
    __builtin_amdgcn_global_load_lds(
        (const __attribute__((address_space(1))) void*)g,
        (__attribute__((address_space(3))) void*)l, 16, 0, 0);
}

// ---------------- fused fp32 -> bf16 casts ----------------
__global__ __launch_bounds__(256) void cast3_bf16(const float* __restrict__ a,
                                                  const float* __restrict__ b,
                                                  const float* __restrict__ c,
                                                  bf16* __restrict__ oa, bf16* __restrict__ ob,
                                                  bf16* __restrict__ oc, int n4) {
    const float* src = blockIdx.y == 0 ? a : blockIdx.y == 1 ? b : c;
    bf16* dst = blockIdx.y == 0 ? oa : blockIdx.y == 1 ? ob : oc;
    int stride = gridDim.x * blockDim.x;
    for (int i = blockIdx.x * blockDim.x + threadIdx.x; i < n4; i += stride) {
        f32x4g v = ((const f32x4g*)src)[i];
        bf16x4 o;
        o[0] = (bf16)v[0]; o[1] = (bf16)v[1]; o[2] = (bf16)v[2]; o[3] = (bf16)v[3];
        ((bf16x4*)dst)[i] = o;
    }
}

__global__ __launch_bounds__(256) void cast4_bf16(const float* __restrict__ a,
                                                  const float* __restrict__ b,
                                                  const float* __restrict__ c,
                                                  const float* __restrict__ d,
                                                  bf16* __restrict__ oa, bf16* __restrict__ ob,
                                                  bf16* __restrict__ oc, bf16* __restrict__ od,
                                                  int n4big, int n4small) {
    const int y = blockIdx.y;
    const float* src = y == 0 ? a : y == 1 ? b : y == 2 ? c : d;
    bf16* dst = y == 0 ? oa : y == 1 ? ob : y == 2 ? oc : od;
    const int n4 = y < 2 ? n4big : n4small;
    int stride = gridDim.x * blockDim.x;
    for (int i = blockIdx.x * blockDim.x + threadIdx.x; i < n4; i += stride) {
        f32x4g v = ((const f32x4g*)src)[i];
        bf16x4 o;
        o[0] = (bf16)v[0]; o[1] = (bf16)v[1]; o[2] = (bf16)v[2]; o[3] = (bf16)v[3];
        ((bf16x4*)dst)[i] = o;
    }
}

// ---------------- NT GEMM core (128x128 tile, BK=32, 4 waves) ----------------
// MODE 0: bf16 row-major C.  MODE 1: f32 row-major C.
// MODE 2: V-transposed bf16 -> VT[((b*4+g)*64+d)*2048 + s]  (fuses vtrans).
template <int MODE>
__device__ __forceinline__ void gemm_body(const bf16* __restrict__ A,
                                          const bf16* __restrict__ Bw,
                                          const float* __restrict__ bias,
                                          void* __restrict__ Cout, int bm, int bn, int N,
                                          int K, bf16* As, bf16* Bs) {
    const int tid = threadIdx.x, wave = tid >> 6, lane = tid & 63;
    const int l15 = lane & 15, lhi = lane >> 4;
    const int wr = (wave >> 1) * 64, wc = (wave & 1) * 64;
    f32x4 acc[4][4] = {};
    const size_t arow0 = (size_t)bm * 128 * K;
    const size_t brow0 = (size_t)bn * 128 * K;

    for (int kt = 0; kt < K; kt += 32) {
#pragma unroll
        for (int i = 0; i < 2; ++i) {
            int base = i * 2048 + wave * 512;
            int flat = base + lane * 8;
            int r = flat >> 5, c = flat & 31;
            gll16(A + arow0 + (size_t)r * K + kt + c, &As[base]);
            gll16(Bw + brow0 + (size_t)r * K + kt + c, &Bs[base]);
        }
        __syncthreads();
        bf16x8 af[4], bfr[4];
#pragma unroll
        for (int mi = 0; mi < 4; ++mi)
            af[mi] = *(const bf16x8_a*)&As[(wr + mi * 16 + l15) * 32 + lhi * 8];
#pragma unroll
        for (int ni = 0; ni < 4; ++ni)
            bfr[ni] = *(const bf16x8_a*)&Bs[(wc + ni * 16 + l15) * 32 + lhi * 8];
#pragma unroll
        for (int mi = 0; mi < 4; ++mi)
#pragma unroll
            for (int ni = 0; ni < 4; ++ni)
                acc[mi][ni] = __builtin_amdgcn_mfma_f32_16x16x32_bf16(
                    af[mi], bfr[ni], acc[mi][ni], 0, 0, 0);
        __syncthreads();
    }
#pragma unroll
    for (int mi = 0; mi < 4; ++mi)
#pragma unroll
        for (int ni = 0; ni < 4; ++ni) {
            const int row0 = bm * 128 + wr + mi * 16 + lhi * 4;  // 4-aligned
            const int col = bn * 128 + wc + ni * 16 + l15;
            if (MODE == 2) {
                // transposed V write: rows are s (consecutive j), col = g*64+d
                bf16x4 o;
#pragma unroll
                for (int j = 0; j < 4; ++j) o[j] = (bf16)(acc[mi][ni][j] + bias[col]);
                const int b_ = row0 >> 11, s_ = row0 & 2047;
                *(bf16x4_a*)&((bf16*)Cout)[(((size_t)b_ * NKVH + (col >> 6)) * DKH +
                                            (col & 63)) *
                                               S_LEN +
                                           s_] = o;
            } else {
#pragma unroll
                for (int j = 0; j < 4; ++j) {
                    int row = row0 + j;
                    float v = acc[mi][ni][j] + bias[col];
                    if (MODE == 1)
                        ((float*)Cout)[(size_t)row * N + col] = v;
                    else
                        ((bf16*)Cout)[(size_t)row * N + col] = (bf16)v;
                }
            }
        }
}

template <int MODE>
__global__ __launch_bounds__(256) void gemm_bt(const bf16* __restrict__ A,
                                               const bf16* __restrict__ Bw,
                                               const float* __restrict__ bias,
                                               void* __restrict__ Cout,
                                               int M, int N, int K) {
    __shared__ bf16 As[4096];
    __shared__ bf16 Bs[4096];
    gemm_body<MODE>(A, Bw, bias, Cout, blockIdx.x, blockIdx.y, N, K, As, Bs);
}

// merged Q/K/V projection: grid (32, 12); by<8 -> Q, 8..9 -> K, 10..11 -> V (V writes VT directly)
__global__ __launch_bounds__(256) void gemm_qkv(const bf16* __restrict__ qx,
                                                const bf16* __restrict__ kx,
                                                const bf16* __restrict__ vx,
                                                const bf16* __restrict__ wqx,
                                                const bf16* __restrict__ wkx,
                                                const bf16* __restrict__ wvx,
                                                const float* __restrict__ bq,
                                                const float* __restrict__ bk,
                                                const float* __restrict__ bv,
                                                bf16* __restrict__ Qp, bf16* __restrict__ Kp,
                                                bf16* __restrict__ VT) {
    __shared__ bf16 As[4096];
    __shared__ bf16 Bs[4096];
    const int by = blockIdx.y;
    if (by < 8) {
        gemm_body<0>(qx, wqx, bq, Qp, blockIdx.x, by, 1024, 1024, As, Bs);
    } else if (by < 10) {
        gemm_body<0>(kx, wkx, bk, Kp, blockIdx.x, by - 8, 256, 1024, As, Bs);
    } else {
        gemm_body<2>(vx, wvx, bv, VT, blockIdx.x, by - 10, 256, 1024, As, Bs);
    }
}

// ---------------- merged attention v8 (R18/R19, unchanged) ----------------
__global__ __launch_bounds__(512, 4) void attn_all(const bf16* __restrict__ Qp,
                                                   const bf16* __restrict__ Kp,
                                                   const bf16* __restrict__ VT,
                                                   float* __restrict__ attn_out,
                                                   bf16* __restrict__ ctx) {
    __shared__ bf16 KV[4][4096];  // 32 KB: pass A = K ring4; pass B = K{0,1}, V{2,3}
    __shared__ bf16 Pw[8][1024];  // 16 KB: per-wave [16 q][64 k] bf16, XOR-swizzled
    const int raw = blockIdx.x;
    const int wg = (raw & 7) * 64 + (raw >> 3);  // 512 % 8 == 0: bijective
    const int bh = wg >> 4;
    const int qt = wg & 15;
    const int h = bh & (NH - 1), b = bh >> 4, g = h >> 2;
    const int tid = threadIdx.x, wave = tid >> 6, lane = tid & 63;
    const int l15 = lane & 15, lhi = lane >> 4;
    const int qw = qt * 128 + wave * 16;
    const int sw = (l15 & 7) << 4;

    const bf16* qb = Qp + (size_t)(b * S_LEN + qw + l15) * DMODEL + h * DKH + lhi * 8;
    bf16x8 aq0 = *(const bf16x8_a*)qb;
    bf16x8 aq1 = *(const bf16x8_a*)(qb + 32);

    const int srow = tid >> 3;
    const int scc = (tid & 7) ^ (srow & 7);
    const bf16* ksrc = Kp + (size_t)(b * S_LEN + srow) * KVD + g * DKH + scc * 8;
    const bf16* vsrc = VT + ((size_t)(b * NKVH + g) * DKH + srow) * S_LEN + scc * 8;

    // ================= pass A: denominators (K ring-4, depth-2 prefetch) =================
    gll16(ksrc, &KV[0][wave * 512]);
    gll16(ksrc + (size_t)64 * KVD, &KV[1][wave * 512]);
    float lsum = 0.f;
    for (int c = 0; c < 32; ++c) {
        if (c < 30) gll16(ksrc + (size_t)((c + 2) * 64) * KVD, &KV[(c + 2) & 3][wave * 512]);
        if (c < 30) { VWAIT(2); } else if (c == 30) { VWAIT(1); } else { VWAIT(0); }
        __builtin_amdgcn_s_barrier();
        const char* kc = (const char*)&KV[c & 3][0];
        f32x4 a0 = {0.f, 0.f, 0.f, 0.f}, a1 = a0, a2 = a0, a3 = a0;
        __builtin_amdgcn_s_setprio(1);
        {
            const int rb = l15 * 128;
            bf16x8 k0 = *(const bf16x8_a*)(kc + rb + ((lhi * 16) ^ sw));
            bf16x8 k1 = *(const bf16x8_a*)(kc + rb + ((lhi * 16 + 64) ^ sw));
            a0 = __builtin_amdgcn_mfma_f32_16x16x32_bf16(k0, aq0, a0, 0, 0, 0);
            a0 = __builtin_amdgcn_mfma_f32_16x16x32_bf16(k1, aq1, a0, 0, 0, 0);
        }
        {
            const int rb = (16 + l15) * 128;
            bf16x8 k0 = *(const bf16x8_a*)(kc + rb + ((lhi * 16) ^ sw));
            bf16x8 k1 = *(const bf16x8_a*)(kc + rb + ((lhi * 16 + 64) ^ sw));
            a1 = __builtin_amdgcn_mfma_f32_16x16x32_bf16(k0, aq0, a1, 0, 0, 0);
            a1 = __builtin_amdgcn_mfma_f32_16x16x32_bf16(k1, aq1, a1, 0, 0, 0);
        }
        {
            const int rb = (32 + l15) * 128;
            bf16x8 k0 = *(const bf16x8_a*)(kc + rb + ((lhi * 16) ^ sw));
            bf16x8 k1 = *(const bf16x8_a*)(kc + rb + ((lhi * 16 + 64) ^ sw));
            a2 = __builtin_amdgcn_mfma_f32_16x16x32_bf16(k0, aq0, a2, 0, 0, 0);
            a2 = __builtin_amdgcn_mfma_f32_16x16x32_bf16(k1, aq1, a2, 0, 0, 0);
        }
        {
            const int rb = (48 + l15) * 128;
            bf16x8 k0 = *(const bf16x8_a*)(kc + rb + ((lhi * 16) ^ sw));
            bf16x8 k1 = *(const bf16x8_a*)(kc + rb + ((lhi * 16 + 64) ^ sw));
            a3 = __builtin_amdgcn_mfma_f32_16x16x32_bf16(k0, aq0, a3, 0, 0, 0);
            a3 = __builtin_amdgcn_mfma_f32_16x16x32_bf16(k1, aq1, a3, 0, 0, 0);
        }
        __builtin_amdgcn_s_setprio(0);
#pragma unroll
        for (int j = 0; j < 4; ++j)
            lsum += __builtin_exp2f(a0[j] * SCALE_LOG2E) + __builtin_exp2f(a1[j] * SCALE_LOG2E) +
                    __builtin_exp2f(a2[j] * SCALE_LOG2E) + __builtin_exp2f(a3[j] * SCALE_LOG2E);
    }
    lsum += __shfl_xor(lsum, 16, 64);
    lsum += __shfl_xor(lsum, 32, 64);
    const float nlog = -__builtin_log2f(lsum);

    // pass-B prologue staging (KV[0]/KV[2] dead for all waves past the c=31 barrier)
    gll16(ksrc, &KV[0][wave * 512]);
    gll16(vsrc, &KV[2][wave * 512]);

    // ================= pass B: probs + PV (K,V ring-2; P wave-private) =================
    f32x4 cacc[4] = {};
    char* pl = (char*)&Pw[wave][0] + l15 * 128;
    char* pls = (char*)&Pw[wave][0];
    const int stslot = lane & 15;
    const int strow4 = lane >> 4;
    float* gstb = attn_out + ((size_t)bh * S_LEN + qw) * S_LEN;

    for (int c = 0; c < 32; ++c) {
        if (c == 0) { VWAIT(0); } else { VWAIT(4); }
        __builtin_amdgcn_s_barrier();
        if (c < 31) {
            gll16(ksrc + (size_t)((c + 1) * 64) * KVD, &KV[(c + 1) & 1][wave * 512]);
            gll16(vsrc + (c + 1) * 64, &KV[2 + ((c + 1) & 1)][wave * 512]);
            __builtin_amdgcn_sched_barrier(0);
        }
        const char* kc = (const char*)&KV[c & 1][0];
        f32x4 a0 = {0.f, 0.f, 0.f, 0.f}, a1 = a0, a2 = a0, a3 = a0;
        __builtin_amdgcn_s_setprio(1);
        {
            const int rb = l15 * 128;
            bf16x8 k0 = *(const bf16x8_a*)(kc + rb + ((lhi * 16) ^ sw));
            bf16x8 k1 = *(const bf16x8_a*)(kc + rb + ((lhi * 16 + 64) ^ sw));
            a0 = __builtin_amdgcn_mfma_f32_16x16x32_bf16(k0, aq0, a0, 0, 0, 0);
            a0 = __builtin_amdgcn_mfma_f32_16x16x32_bf16(k1, aq1, a0, 0, 0, 0);
        }
        {
            const int rb = (16 + l15) * 128;
            bf16x8 k0 = *(const bf16x8_a*)(kc + rb + ((lhi * 16) ^ sw));
            bf16x8 k1 = *(const bf16x8_a*)(kc + rb + ((lhi * 16 + 64) ^ sw));
            a1 = __builtin_amdgcn_mfma_f32_16x16x32_bf16(k0, aq0, a1, 0, 0, 0);
            a1 = __builtin_amdgcn_mfma_f32_16x16x32_bf16(k1, aq1, a1, 0, 0, 0);
        }
        {
            const int rb = (32 + l15) * 128;
            bf16x8 k0 = *(const bf16x8_a*)(kc + rb + ((lhi * 16) ^ sw));
            bf16x8 k1 = *(const bf16x8_a*)(kc + rb + ((lhi * 16 + 64) ^ sw));
            a2 = __builtin_amdgcn_mfma_f32_16x16x32_bf16(k0, aq0, a2, 0, 0, 0);
            a2 = __builtin_amdgcn_mfma_f32_16x16x32_bf16(k1, aq1, a2, 0, 0, 0);
        }
        {
            const int rb = (48 + l15) * 128;
            bf16x8 k0 = *(const bf16x8_a*)(kc + rb + ((lhi * 16) ^ sw));
            bf16x8 k1 = *(const bf16x8_a*)(kc + rb + ((lhi * 16 + 64) ^ sw));
            a3 = __builtin_amdgcn_mfma_f32_16x16x32_bf16(k0, aq0, a3, 0, 0, 0);
            a3 = __builtin_amdgcn_mfma_f32_16x16x32_bf16(k1, aq1, a3, 0, 0, 0);
        }
        __builtin_amdgcn_s_setprio(0);
        {
            bf16x4 p0, p1, p2, p3;
#pragma unroll
            for (int j = 0; j < 4; ++j) {
                p0[j] = (bf16)__builtin_exp2f(__builtin_fmaf(a0[j], SCALE_LOG2E, nlog));
                p1[j] = (bf16)__builtin_exp2f(__builtin_fmaf(a1[j], SCALE_LOG2E, nlog));
                p2[j] = (bf16)__builtin_exp2f(__builtin_fmaf(a2[j], SCALE_LOG2E, nlog));
                p3[j] = (bf16)__builtin_exp2f(__builtin_fmaf(a3[j], SCALE_LOG2E, nlog));
            }
            *(bf16x4_a*)(pl + ((0 * 32 + lhi * 8) ^ sw)) = p0;
            *(bf16x4_a*)(pl + ((1 * 32 + lhi * 8) ^ sw)) = p1;
            *(bf16x4_a*)(pl + ((2 * 32 + lhi * 8) ^ sw)) = p2;
            *(bf16x4_a*)(pl + ((3 * 32 + lhi * 8) ^ sw)) = p3;
        }
        bf16x8 ap0 = *(const bf16x8_a*)(pl + ((lhi * 16) ^ sw));
        bf16x8 ap1 = *(const bf16x8_a*)(pl + ((lhi * 16 + 64) ^ sw));
        const char* vc = (const char*)&KV[2 + (c & 1)][0];
        __builtin_amdgcn_s_setprio(1);
#pragma unroll
        for (int t = 0; t < 4; ++t) {
            const int vb = (t * 16 + l15) * 128;
            bf16x8 v0 = *(const bf16x8_a*)(vc + vb + ((lhi * 16) ^ sw));
            bf16x8 v1 = *(const bf16x8_a*)(vc + vb + ((lhi * 16 + 64) ^ sw));
            cacc[t] = __builtin_amdgcn_mfma_f32_16x16x32_bf16(ap0, v0, cacc[t], 0, 0, 0);
            cacc[t] = __builtin_amdgcn_mfma_f32_16x16x32_bf16(ap1, v1, cacc[t], 0, 0, 0);
        }
        __builtin_amdgcn_s_setprio(0);
#pragma unroll
        for (int t = 0; t < 4; ++t) {
            const int r = t * 4 + strow4;
            bf16x4 pv4 =
                *(const bf16x4_a*)(pls + r * 128 + ((stslot * 8) ^ ((r & 7) << 4)));
            f32x4 pf4;
#pragma unroll
            for (int j = 0; j < 4; ++j) pf4[j] = (float)pv4[j];
            *(f32x4g*)(gstb + (size_t)r * S_LEN + c * 64 + stslot * 4) = pf4;
        }
    }
#pragma unroll
    for (int t = 0; t < 4; ++t)
#pragma unroll
        for (int j = 0; j < 4; ++j) {
            int row = qw + lhi * 4 + j;
            ctx[(size_t)(b * S_LEN + row) * DMODEL + h * DKH + t * 16 + l15] =
                (bf16)cacc[t][j];
        }
}

extern "C" void kernel_launch(void* const* d_in, const int* in_sizes, int n_in,
                              void* d_out, int out_size, void* d_ws, size_t ws_size,
                              hipStream_t stream) {
    const float* query = (const float*)d_in[0];
    const float* key_i = (const float*)d_in[1];
    const float* value = (const float*)d_in[2];
    const float* Wq = (const float*)d_in[3];
    const float* bq = (const float*)d_in[4];
    const float* Wk = (const float*)d_in[5];
    const float* bk = (const float*)d_in[6];
    const float* Wv = (const float*)d_in[7];
    const float* bv = (const float*)d_in[8];
    const float* Wo = (const float*)d_in[9];
    const float* bo = (const float*)d_in[10];

    char* ws = (char*)d_ws;
    bf16* qx = (bf16*)(ws + 0);
    bf16* kx = (bf16*)(ws + ((size_t)8 << 20));
    bf16* vx = (bf16*)(ws + ((size_t)16 << 20));
    bf16* wqx = (bf16*)(ws + ((size_t)32 << 20));
    bf16* wkx = (bf16*)(ws + ((size_t)34 << 20));
    bf16* wvx = (bf16*)(ws + ((size_t)34 << 20) + ((size_t)512 << 10));
    bf16* wox = (bf16*)(ws + ((size_t)35 << 20));
    bf16* Qp = (bf16*)(ws + ((size_t)37 << 20));
    bf16* Kp = (bf16*)(ws + ((size_t)45 << 20));
    bf16* VT = (bf16*)(ws + ((size_t)49 << 20));
    bf16* ctxb = (bf16*)(ws + ((size_t)51 << 20));

    const int BS = 2 * S_LEN;  // 4096 rows

    cast3_bf16<<<dim3(1024, 3), 256, 0, stream>>>(query, key_i, value, qx, kx, vx,
                                                  BS * DMODEL / 4);
    cast4_bf16<<<dim3(1024, 4), 256, 0, stream>>>(Wq, Wo, Wk, Wv, wqx, wox, wkx, wvx,
                                                  DMODEL * DMODEL / 4, KVD * DMODEL / 4);

    gemm_qkv<<<dim3(32, 12), 256, 0, stream>>>(qx, kx, vx, wqx, wkx, wvx, bq, bk, bv, Qp, Kp,
                                               VT);

    float* attn_out = (float*)d_out + (size_t)BS * DMODEL;
    attn_all<<<512, 512, 0, stream>>>(Qp, Kp, VT, attn_out, ctxb);

    gemm_bt<1><<<dim3(32, 8), 256, 0, stream>>>(ctxb, wox, bo, (float*)d_out, BS, DMODEL, DMODEL);
}

// Round 24
// 232.975 us; speedup vs baseline: 1.0398x; 1.0136x over previous
//
#include <hip/hip_runtime.h>

#define S_LEN 2048
#define DMODEL 1024
#define NH 16
#define NKVH 4
#define DKH 64
#define KVD 256
#define SCALE_LOG2E 0.18033688f  // (1/sqrt(64)) * log2(e)

typedef __bf16 bf16;
typedef bf16  bf16x8 __attribute__((ext_vector_type(8)));
typedef bf16  bf16x4 __attribute__((ext_vector_type(4)));
typedef float f32x4  __attribute__((ext_vector_type(4)));
typedef bf16x8 bf16x8_a __attribute__((may_alias));
typedef bf16x4 bf16x4_a __attribute__((may_alias));
typedef float f32x4g __attribute__((ext_vector_type(4), may_alias));

#define VWAIT(N)                                             \
    do {                                                     \
        asm volatile("s_waitcnt vmcnt(" #N ")" ::: "memory");\
        __builtin_amdgcn_sched_barrier(0);                   \
    } while (0)

__device__ __forceinline__ void gll16(const bf16* g, bf16* l) {
    __builtin_amdgcn_global_load_lds(
        (const __attribute__((address_space(1))) void*)g,
        (__attribute__((address_space(3))) void*)l, 16, 0, 0);
}

// ---------------- fused fp32 -> bf16 casts ----------------
__global__ __launch_bounds__(256) void cast3_bf16(const float* __restrict__ a,
                                                  const float* __restrict__ b,
                                                  const float* __restrict__ c,
                                                  bf16* __restrict__ oa, bf16* __restrict__ ob,
                                                  bf16* __restrict__ oc, int n4) {
    const float* src = blockIdx.y == 0 ? a : blockIdx.y == 1 ? b : c;
    bf16* dst = blockIdx.y == 0 ? oa : blockIdx.y == 1 ? ob : oc;
    int stride = gridDim.x * blockDim.x;
    for (int i = blockIdx.x * blockDim.x + threadIdx.x; i < n4; i += stride) {
        f32x4g v = ((const f32x4g*)src)[i];
        bf16x4 o;
        o[0] = (bf16)v[0]; o[1] = (bf16)v[1]; o[2] = (bf16)v[2]; o[3] = (bf16)v[3];
        ((bf16x4*)dst)[i] = o;
    }
}

__global__ __launch_bounds__(256) void cast4_bf16(const float* __restrict__ a,
                                                  const float* __restrict__ b,
                                                  const float* __restrict__ c,
                                                  const float* __restrict__ d,
                                                  bf16* __restrict__ oa, bf16* __restrict__ ob,
                                                  bf16* __restrict__ oc, bf16* __restrict__ od,
                                                  int n4big, int n4small) {
    const int y = blockIdx.y;
    const float* src = y == 0 ? a : y == 1 ? b : y == 2 ? c : d;
    bf16* dst = y == 0 ? oa : y == 1 ? ob : y == 2 ? oc : od;
    const int n4 = y < 2 ? n4big : n4small;
    int stride = gridDim.x * blockDim.x;
    for (int i = blockIdx.x * blockDim.x + threadIdx.x; i < n4; i += stride) {
        f32x4g v = ((const f32x4g*)src)[i];
        bf16x4 o;
        o[0] = (bf16)v[0]; o[1] = (bf16)v[1]; o[2] = (bf16)v[2]; o[3] = (bf16)v[3];
        ((bf16x4*)dst)[i] = o;
    }
}

// ---------------- NT GEMM core (128x128 tile, BK=32, 4 waves) ----------------
// MODE 0: bf16 row-major C.  MODE 1: f32 row-major C.
// MODE 2: V-transposed bf16 -> VT[((b*4+g)*64+d)*2048 + s]  (fuses vtrans).
template <int MODE>
__device__ __forceinline__ void gemm_body(const bf16* __restrict__ A,
                                          const bf16* __restrict__ Bw,
                                          const float* __restrict__ bias,
                                          void* __restrict__ Cout, int bm, int bn, int N,
                                          int K, bf16* As, bf16* Bs) {
    const int tid = threadIdx.x, wave = tid >> 6, lane = tid & 63;
    const int l15 = lane & 15, lhi = lane >> 4;
    const int wr = (wave >> 1) * 64, wc = (wave & 1) * 64;
    f32x4 acc[4][4] = {};
    const size_t arow0 = (size_t)bm * 128 * K;
    const size_t brow0 = (size_t)bn * 128 * K;

    for (int kt = 0; kt < K; kt += 32) {
#pragma unroll
        for (int i = 0; i < 2; ++i) {
            int base = i * 2048 + wave * 512;
            int flat = base + lane * 8;
            int r = flat >> 5, c = flat & 31;
            gll16(A + arow0 + (size_t)r * K + kt + c, &As[base]);
            gll16(Bw + brow0 + (size_t)r * K + kt + c, &Bs[base]);
        }
        __syncthreads();
        bf16x8 af[4], bfr[4];
#pragma unroll
        for (int mi = 0; mi < 4; ++mi)
            af[mi] = *(const bf16x8_a*)&As[(wr + mi * 16 + l15) * 32 + lhi * 8];
#pragma unroll
        for (int ni = 0; ni < 4; ++ni)
            bfr[ni] = *(const bf16x8_a*)&Bs[(wc + ni * 16 + l15) * 32 + lhi * 8];
#pragma unroll
        for (int mi = 0; mi < 4; ++mi)
#pragma unroll
            for (int ni = 0; ni < 4; ++ni)
                acc[mi][ni] = __builtin_amdgcn_mfma_f32_16x16x32_bf16(
                    af[mi], bfr[ni], acc[mi][ni], 0, 0, 0);
        __syncthreads();
    }
#pragma unroll
    for (int mi = 0; mi < 4; ++mi)
#pragma unroll
        for (int ni = 0; ni < 4; ++ni) {
            const int row0 = bm * 128 + wr + mi * 16 + lhi * 4;  // 4-aligned
            const int col = bn * 128 + wc + ni * 16 + l15;
            if (MODE == 2) {
                bf16x4 o;
#pragma unroll
                for (int j = 0; j < 4; ++j) o[j] = (bf16)(acc[mi][ni][j] + bias[col]);
                const int b_ = row0 >> 11, s_ = row0 & 2047;
                *(bf16x4_a*)&((bf16*)Cout)[(((size_t)b_ * NKVH + (col >> 6)) * DKH +
                                            (col & 63)) *
                                               S_LEN +
                                           s_] = o;
            } else {
#pragma unroll
                for (int j = 0; j < 4; ++j) {
                    int row = row0 + j;
                    float v = acc[mi][ni][j] + bias[col];
                    if (MODE == 1)
                        ((float*)Cout)[(size_t)row * N + col] = v;
                    else
                        ((bf16*)Cout)[(size_t)row * N + col] = (bf16)v;
                }
            }
        }
}

template <int MODE>
__global__ __launch_bounds__(256) void gemm_bt(const bf16* __restrict__ A,
                                               const bf16* __restrict__ Bw,
                                               const float* __restrict__ bias,
                                               void* __restrict__ Cout,
                                               int M, int N, int K) {
    __shared__ bf16 As[4096];
    __shared__ bf16 Bs[4096];
    gemm_body<MODE>(A, Bw, bias, Cout, blockIdx.x, blockIdx.y, N, K, As, Bs);
}

// merged Q/K/V projection: grid (32, 12); by<8 -> Q, 8..9 -> K, 10..11 -> V (V writes VT directly)
__global__ __launch_bounds__(256) void gemm_qkv(const bf16* __restrict__ qx,
                                                const bf16* __restrict__ kx,
                                                const bf16* __restrict__ vx,
                                                const bf16* __restrict__ wqx,
                                                const bf16* __restrict__ wkx,
                                                const bf16* __restrict__ wvx,
                                                const float* __restrict__ bq,
                                                const float* __restrict__ bk,
                                                const float* __restrict__ bv,
                                                bf16* __restrict__ Qp, bf16* __restrict__ Kp,
                                                bf16* __restrict__ VT) {
    __shared__ bf16 As[4096];
    __shared__ bf16 Bs[4096];
    const int by = blockIdx.y;
    if (by < 8) {
        gemm_body<0>(qx, wqx, bq, Qp, blockIdx.x, by, 1024, 1024, As, Bs);
    } else if (by < 10) {
        gemm_body<0>(kx, wkx, bk, Kp, blockIdx.x, by - 8, 256, 1024, As, Bs);
    } else {
        gemm_body<2>(vx, wvx, bv, VT, blockIdx.x, by - 10, 256, 1024, As, Bs);
    }
}

// ---------------- merged attention (R23 structure; NONTEMPORAL streaming stores) ----------------
__global__ __launch_bounds__(512, 4) void attn_all(const bf16* __restrict__ Qp,
                                                   const bf16* __restrict__ Kp,
                                                   const bf16* __restrict__ VT,
                                                   float* __restrict__ attn_out,
                                                   bf16* __restrict__ ctx) {
    __shared__ bf16 KV[4][4096];  // 32 KB: pass A = K ring4; pass B = K{0,1}, V{2,3}
    __shared__ bf16 Pw[8][1024];  // 16 KB: per-wave [16 q][64 k] bf16, XOR-swizzled
    const int raw = blockIdx.x;
    const int wg = (raw & 7) * 64 + (raw >> 3);  // 512 % 8 == 0: bijective
    const int bh = wg >> 4;
    const int qt = wg & 15;
    const int h = bh & (NH - 1), b = bh >> 4, g = h >> 2;
    const int tid = threadIdx.x, wave = tid >> 6, lane = tid & 63;
    const int l15 = lane & 15, lhi = lane >> 4;
    const int qw = qt * 128 + wave * 16;
    const int sw = (l15 & 7) << 4;

    const bf16* qb = Qp + (size_t)(b * S_LEN + qw + l15) * DMODEL + h * DKH + lhi * 8;
    bf16x8 aq0 = *(const bf16x8_a*)qb;
    bf16x8 aq1 = *(const bf16x8_a*)(qb + 32);

    const int srow = tid >> 3;
    const int scc = (tid & 7) ^ (srow & 7);
    const bf16* ksrc = Kp + (size_t)(b * S_LEN + srow) * KVD + g * DKH + scc * 8;
    const bf16* vsrc = VT + ((size_t)(b * NKVH + g) * DKH + srow) * S_LEN + scc * 8;

    // ================= pass A: denominators (K ring-4, depth-2 prefetch) =================
    gll16(ksrc, &KV[0][wave * 512]);
    gll16(ksrc + (size_t)64 * KVD, &KV[1][wave * 512]);
    float lsum = 0.f;
    for (int c = 0; c < 32; ++c) {
        if (c < 30) gll16(ksrc + (size_t)((c + 2) * 64) * KVD, &KV[(c + 2) & 3][wave * 512]);
        if (c < 30) { VWAIT(2); } else if (c == 30) { VWAIT(1); } else { VWAIT(0); }
        __builtin_amdgcn_s_barrier();
        const char* kc = (const char*)&KV[c & 3][0];
        f32x4 a0 = {0.f, 0.f, 0.f, 0.f}, a1 = a0, a2 = a0, a3 = a0;
        __builtin_amdgcn_s_setprio(1);
        {
            const int rb = l15 * 128;
            bf16x8 k0 = *(const bf16x8_a*)(kc + rb + ((lhi * 16) ^ sw));
            bf16x8 k1 = *(const bf16x8_a*)(kc + rb + ((lhi * 16 + 64) ^ sw));
            a0 = __builtin_amdgcn_mfma_f32_16x16x32_bf16(k0, aq0, a0, 0, 0, 0);
            a0 = __builtin_amdgcn_mfma_f32_16x16x32_bf16(k1, aq1, a0, 0, 0, 0);
        }
        {
            const int rb = (16 + l15) * 128;
            bf16x8 k0 = *(const bf16x8_a*)(kc + rb + ((lhi * 16) ^ sw));
            bf16x8 k1 = *(const bf16x8_a*)(kc + rb + ((lhi * 16 + 64) ^ sw));
            a1 = __builtin_amdgcn_mfma_f32_16x16x32_bf16(k0, aq0, a1, 0, 0, 0);
            a1 = __builtin_amdgcn_mfma_f32_16x16x32_bf16(k1, aq1, a1, 0, 0, 0);
        }
        {
            const int rb = (32 + l15) * 128;
            bf16x8 k0 = *(const bf16x8_a*)(kc + rb + ((lhi * 16) ^ sw));
            bf16x8 k1 = *(const bf16x8_a*)(kc + rb + ((lhi * 16 + 64) ^ sw));
            a2 = __builtin_amdgcn_mfma_f32_16x16x32_bf16(k0, aq0, a2, 0, 0, 0);
            a2 = __builtin_amdgcn_mfma_f32_16x16x32_bf16(k1, aq1, a2, 0, 0, 0);
        }
        {
            const int rb = (48 + l15) * 128;
            bf16x8 k0 = *(const bf16x8_a*)(kc + rb + ((lhi * 16) ^ sw));
            bf16x8 k1 = *(const bf16x8_a*)(kc + rb + ((lhi * 16 + 64) ^ sw));
            a3 = __builtin_amdgcn_mfma_f32_16x16x32_bf16(k0, aq0, a3, 0, 0, 0);
            a3 = __builtin_amdgcn_mfma_f32_16x16x32_bf16(k1, aq1, a3, 0, 0, 0);
        }
        __builtin_amdgcn_s_setprio(0);
#pragma unroll
        for (int j = 0; j < 4; ++j)
            lsum += __builtin_exp2f(a0[j] * SCALE_LOG2E) + __builtin_exp2f(a1[j] * SCALE_LOG2E) +
                    __builtin_exp2f(a2[j] * SCALE_LOG2E) + __builtin_exp2f(a3[j] * SCALE_LOG2E);
    }
    lsum += __shfl_xor(lsum, 16, 64);
    lsum += __shfl_xor(lsum, 32, 64);
    const float nlog = -__builtin_log2f(lsum);

    // pass-B prologue staging (KV[0]/KV[2] dead for all waves past the c=31 barrier)
    gll16(ksrc, &KV[0][wave * 512]);
    gll16(vsrc, &KV[2][wave * 512]);

    // ================= pass B: probs + PV (K,V ring-2; P wave-private) =================
    f32x4 cacc[4] = {};
    char* pl = (char*)&Pw[wave][0] + l15 * 128;
    char* pls = (char*)&Pw[wave][0];
    const int stslot = lane & 15;
    const int strow4 = lane >> 4;
    float* gstb = attn_out + ((size_t)bh * S_LEN + qw) * S_LEN;

    for (int c = 0; c < 32; ++c) {
        if (c == 0) { VWAIT(0); } else { VWAIT(4); }
        __builtin_amdgcn_s_barrier();
        if (c < 31) {
            gll16(ksrc + (size_t)((c + 1) * 64) * KVD, &KV[(c + 1) & 1][wave * 512]);
            gll16(vsrc + (c + 1) * 64, &KV[2 + ((c + 1) & 1)][wave * 512]);
            __builtin_amdgcn_sched_barrier(0);
        }
        const char* kc = (const char*)&KV[c & 1][0];
        f32x4 a0 = {0.f, 0.f, 0.f, 0.f}, a1 = a0, a2 = a0, a3 = a0;
        __builtin_amdgcn_s_setprio(1);
        {
            const int rb = l15 * 128;
            bf16x8 k0 = *(const bf16x8_a*)(kc + rb + ((lhi * 16) ^ sw));
            bf16x8 k1 = *(const bf16x8_a*)(kc + rb + ((lhi * 16 + 64) ^ sw));
            a0 = __builtin_amdgcn_mfma_f32_16x16x32_bf16(k0, aq0, a0, 0, 0, 0);
            a0 = __builtin_amdgcn_mfma_f32_16x16x32_bf16(k1, aq1, a0, 0, 0, 0);
        }
        {
            const int rb = (16 + l15) * 128;
            bf16x8 k0 = *(const bf16x8_a*)(kc + rb + ((lhi * 16) ^ sw));
            bf16x8 k1 = *(const bf16x8_a*)(kc + rb + ((lhi * 16 + 64) ^ sw));
            a1 = __builtin_amdgcn_mfma_f32_16x16x32_bf16(k0, aq0, a1, 0, 0, 0);
            a1 = __builtin_amdgcn_mfma_f32_16x16x32_bf16(k1, aq1, a1, 0, 0, 0);
        }
        {
            const int rb = (32 + l15) * 128;
            bf16x8 k0 = *(const bf16x8_a*)(kc + rb + ((lhi * 16) ^ sw));
            bf16x8 k1 = *(const bf16x8_a*)(kc + rb + ((lhi * 16 + 64) ^ sw));
            a2 = __builtin_amdgcn_mfma_f32_16x16x32_bf16(k0, aq0, a2, 0, 0, 0);
            a2 = __builtin_amdgcn_mfma_f32_16x16x32_bf16(k1, aq1, a2, 0, 0, 0);
        }
        {
            const int rb = (48 + l15) * 128;
            bf16x8 k0 = *(const bf16x8_a*)(kc + rb + ((lhi * 16) ^ sw));
            bf16x8 k1 = *(const bf16x8_a*)(kc + rb + ((lhi * 16 + 64) ^ sw));
            a3 = __builtin_amdgcn_mfma_f32_16x16x32_bf16(k0, aq0, a3, 0, 0, 0);
            a3 = __builtin_amdgcn_mfma_f32_16x16x32_bf16(k1, aq1, a3, 0, 0, 0);
        }
        __builtin_amdgcn_s_setprio(0);
        {
            bf16x4 p0, p1, p2, p3;
#pragma unroll
            for (int j = 0; j < 4; ++j) {
                p0[j] = (bf16)__builtin_exp2f(__builtin_fmaf(a0[j], SCALE_LOG2E, nlog));
                p1[j] = (bf16)__builtin_exp2f(__builtin_fmaf(a1[j], SCALE_LOG2E, nlog));
                p2[j] = (bf16)__builtin_exp2f(__builtin_fmaf(a2[j], SCALE_LOG2E, nlog));
                p3[j] = (bf16)__builtin_exp2f(__builtin_fmaf(a3[j], SCALE_LOG2E, nlog));
            }
            *(bf16x4_a*)(pl + ((0 * 32 + lhi * 8) ^ sw)) = p0;
            *(bf16x4_a*)(pl + ((1 * 32 + lhi * 8) ^ sw)) = p1;
            *(bf16x4_a*)(pl + ((2 * 32 + lhi * 8) ^ sw)) = p2;
            *(bf16x4_a*)(pl + ((3 * 32 + lhi * 8) ^ sw)) = p3;
        }
        bf16x8 ap0 = *(const bf16x8_a*)(pl + ((lhi * 16) ^ sw));
        bf16x8 ap1 = *(const bf16x8_a*)(pl + ((lhi * 16 + 64) ^ sw));
        const char* vc = (const char*)&KV[2 + (c & 1)][0];
        __builtin_amdgcn_s_setprio(1);
#pragma unroll
        for (int t = 0; t < 4; ++t) {
            const int vb = (t * 16 + l15) * 128;
            bf16x8 v0 = *(const bf16x8_a*)(vc + vb + ((lhi * 16) ^ sw));
            bf16x8 v1 = *(const bf16x8_a*)(vc + vb + ((lhi * 16 + 64) ^ sw));
            cacc[t] = __builtin_amdgcn_mfma_f32_16x16x32_bf16(ap0, v0, cacc[t], 0, 0, 0);
            cacc[t] = __builtin_amdgcn_mfma_f32_16x16x32_bf16(ap1, v1, cacc[t], 0, 0, 0);
        }
        __builtin_amdgcn_s_setprio(0);
#pragma unroll
        for (int t = 0; t < 4; ++t) {
            const int r = t * 4 + strow4;
            bf16x4 pv4 =
                *(const bf16x4_a*)(pls + r * 128 + ((stslot * 8) ^ ((r & 7) << 4)));
            f32x4 pf4;
#pragma unroll
            for (int j = 0; j < 4; ++j) pf4[j] = (float)pv4[j];
            __builtin_nontemporal_store(
                pf4, (f32x4g*)(gstb + (size_t)r * S_LEN + c * 64 + stslot * 4));
        }
    }
#pragma unroll
    for (int t = 0; t < 4; ++t)
#pragma unroll
        for (int j = 0; j < 4; ++j) {
            int row = qw + lhi * 4 + j;
            __builtin_nontemporal_store(
                (bf16)cacc[t][j],
                &ctx[(size_t)(b * S_LEN + row) * DMODEL + h * DKH + t * 16 + l15]);
        }
}

extern "C" void kernel_launch(void* const* d_in, const int* in_sizes, int n_in,
                              void* d_out, int out_size, void* d_ws, size_t ws_size,
                              hipStream_t stream) {
    const float* query = (const float*)d_in[0];
    const float* key_i = (const float*)d_in[1];
    const float* value = (const float*)d_in[2];
    const float* Wq = (const float*)d_in[3];
    const float* bq = (const float*)d_in[4];
    const float* Wk = (const float*)d_in[5];
    const float* bk = (const float*)d_in[6];
    const float* Wv = (const float*)d_in[7];
    const float* bv = (const float*)d_in[8];
    const float* Wo = (const float*)d_in[9];
    const float* bo = (const float*)d_in[10];

    char* ws = (char*)d_ws;
    bf16* qx = (bf16*)(ws + 0);
    bf16* kx = (bf16*)(ws + ((size_t)8 << 20));
    bf16* vx = (bf16*)(ws + ((size_t)16 << 20));
    bf16* wqx = (bf16*)(ws + ((size_t)32 << 20));
    bf16* wkx = (bf16*)(ws + ((size_t)34 << 20));
    bf16* wvx = (bf16*)(ws + ((size_t)34 << 20) + ((size_t)512 << 10));
    bf16* wox = (bf16*)(ws + ((size_t)35 << 20));
    bf16* Qp = (bf16*)(ws + ((size_t)37 << 20));
    bf16* Kp = (bf16*)(ws + ((size_t)45 << 20));
    bf16* VT = (bf16*)(ws + ((size_t)49 << 20));
    bf16* ctxb = (bf16*)(ws + ((size_t)51 << 20));

    const int BS = 2 * S_LEN;  // 4096 rows

    cast3_bf16<<<dim3(1024, 3), 256, 0, stream>>>(query, key_i, value, qx, kx, vx,
                                                  BS * DMODEL / 4);
    cast4_bf16<<<dim3(1024, 4), 256, 0, stream>>>(Wq, Wo, Wk, Wv, wqx, wox, wkx, wvx,
                                                  DMODEL * DMODEL / 4, KVD * DMODEL / 4);

    gemm_qkv<<<dim3(32, 12), 256, 0, stream>>>(qx, kx, vx, wqx, wkx, wvx, bq, bk, bv, Qp, Kp,
                                               VT);

    float* attn_out = (float*)d_out + (size_t)BS * DMODEL;
    attn_all<<<512, 512, 0, stream>>>(Qp, Kp, VT, attn_out, ctxb);

    gemm_bt<1><<<dim3(32, 8), 256, 0, stream>>>(ctxb, wox, bo, (float*)d_out, BS, DMODEL, DMODEL);
}

// Round 25
// 229.306 us; speedup vs baseline: 1.0565x; 1.0160x over previous
//
#include <hip/hip_runtime.h>

#define S_LEN 2048
#define DMODEL 1024
#define NH 16
#define NKVH 4
#define DKH 64
#define KVD 256
#define SCALE_LOG2E 0.18033688f  // (1/sqrt(64)) * log2(e)

typedef __bf16 bf16;
typedef bf16  bf16x8 __attribute__((ext_vector_type(8)));
typedef bf16  bf16x4 __attribute__((ext_vector_type(4)));
typedef float f32x4  __attribute__((ext_vector_type(4)));
typedef bf16x8 bf16x8_a __attribute__((may_alias));
typedef bf16x4 bf16x4_a __attribute__((may_alias));
typedef float f32x4g __attribute__((ext_vector_type(4), may_alias));

#define VWAIT(N)                                             \
    do {                                                     \
        asm volatile("s_waitcnt vmcnt(" #N ")" ::: "memory");\
        __builtin_amdgcn_sched_barrier(0);                   \
    } while (0)

__device__ __forceinline__ void gll16(const bf16* g, bf16* l) {
    __builtin_amdgcn_global_load_lds(
        (const __attribute__((address_space(1))) void*)g,
        (__attribute__((address_space(3))) void*)l, 16, 0, 0);
}

// ---------------- all seven fp32 -> bf16 casts in ONE launch ----------------
__global__ __launch_bounds__(256) void cast_all(const float* __restrict__ i0,
                                                const float* __restrict__ i1,
                                                const float* __restrict__ i2,
                                                const float* __restrict__ i3,
                                                const float* __restrict__ i4,
                                                const float* __restrict__ i5,
                                                const float* __restrict__ i6,
                                                bf16* __restrict__ o0, bf16* __restrict__ o1,
                                                bf16* __restrict__ o2, bf16* __restrict__ o3,
                                                bf16* __restrict__ o4, bf16* __restrict__ o5,
                                                bf16* __restrict__ o6, int nbig, int nmid,
                                                int nsmall) {
    const int y = blockIdx.y;
    const float* src;
    bf16* dst;
    int n4;
    switch (y) {
        case 0: src = i0; dst = o0; n4 = nbig; break;
        case 1: src = i1; dst = o1; n4 = nbig; break;
        case 2: src = i2; dst = o2; n4 = nbig; break;
        case 3: src = i3; dst = o3; n4 = nmid; break;
        case 4: src = i4; dst = o4; n4 = nmid; break;
        case 5: src = i5; dst = o5; n4 = nsmall; break;
        default: src = i6; dst = o6; n4 = nsmall; break;
    }
    int stride = gridDim.x * blockDim.x;
    for (int i = blockIdx.x * blockDim.x + threadIdx.x; i < n4; i += stride) {
        f32x4g v = ((const f32x4g*)src)[i];
        bf16x4 o;
        o[0] = (bf16)v[0]; o[1] = (bf16)v[1]; o[2] = (bf16)v[2]; o[3] = (bf16)v[3];
        ((bf16x4*)dst)[i] = o;
    }
}

// ---------------- NT GEMM core (128x128 tile, BK=32, 4 waves) ----------------
// MODE 0: bf16 row-major C.  MODE 1: f32 row-major C (nontemporal).
// MODE 2: V-transposed bf16 -> VT[((b*4+g)*64+d)*2048 + s]  (fuses vtrans).
template <int MODE>
__device__ __forceinline__ void gemm_body(const bf16* __restrict__ A,
                                          const bf16* __restrict__ Bw,
                                          const float* __restrict__ bias,
                                          void* __restrict__ Cout, int bm, int bn, int N,
                                          int K, bf16* As, bf16* Bs) {
    const int tid = threadIdx.x, wave = tid >> 6, lane = tid & 63;
    const int l15 = lane & 15, lhi = lane >> 4;
    const int wr = (wave >> 1) * 64, wc = (wave & 1) * 64;
    f32x4 acc[4][4] = {};
    const size_t arow0 = (size_t)bm * 128 * K;
    const size_t brow0 = (size_t)bn * 128 * K;

    for (int kt = 0; kt < K; kt += 32) {
#pragma unroll
        for (int i = 0; i < 2; ++i) {
            int base = i * 2048 + wave * 512;
            int flat = base + lane * 8;
            int r = flat >> 5, c = flat & 31;
            gll16(A + arow0 + (size_t)r * K + kt + c, &As[base]);
            gll16(Bw + brow0 + (size_t)r * K + kt + c, &Bs[base]);
        }
        __syncthreads();
        bf16x8 af[4], bfr[4];
#pragma unroll
        for (int mi = 0; mi < 4; ++mi)
            af[mi] = *(const bf16x8_a*)&As[(wr + mi * 16 + l15) * 32 + lhi * 8];
#pragma unroll
        for (int ni = 0; ni < 4; ++ni)
            bfr[ni] = *(const bf16x8_a*)&Bs[(wc + ni * 16 + l15) * 32 + lhi * 8];
#pragma unroll
        for (int mi = 0; mi < 4; ++mi)
#pragma unroll
            for (int ni = 0; ni < 4; ++ni)
                acc[mi][ni] = __builtin_amdgcn_mfma_f32_16x16x32_bf16(
                    af[mi], bfr[ni], acc[mi][ni], 0, 0, 0);
        __syncthreads();
    }
#pragma unroll
    for (int mi = 0; mi < 4; ++mi)
#pragma unroll
        for (int ni = 0; ni < 4; ++ni) {
            const int row0 = bm * 128 + wr + mi * 16 + lhi * 4;  // 4-aligned
            const int col = bn * 128 + wc + ni * 16 + l15;
            if (MODE == 2) {
                bf16x4 o;
#pragma unroll
                for (int j = 0; j < 4; ++j) o[j] = (bf16)(acc[mi][ni][j] + bias[col]);
                const int b_ = row0 >> 11, s_ = row0 & 2047;
                *(bf16x4_a*)&((bf16*)Cout)[(((size_t)b_ * NKVH + (col >> 6)) * DKH +
                                            (col & 63)) *
                                               S_LEN +
                                           s_] = o;
            } else {
#pragma unroll
                for (int j = 0; j < 4; ++j) {
                    int row = row0 + j;
                    float v = acc[mi][ni][j] + bias[col];
                    if (MODE == 1)
                        __builtin_nontemporal_store(
                            v, &((float*)Cout)[(size_t)row * N + col]);
                    else
                        ((bf16*)Cout)[(size_t)row * N + col] = (bf16)v;
                }
            }
        }
}

template <int MODE>
__global__ __launch_bounds__(256) void gemm_bt(const bf16* __restrict__ A,
                                               const bf16* __restrict__ Bw,
                                               const float* __restrict__ bias,
                                               void* __restrict__ Cout,
                                               int M, int N, int K) {
    __shared__ bf16 As[4096];
    __shared__ bf16 Bs[4096];
    gemm_body<MODE>(A, Bw, bias, Cout, blockIdx.x, blockIdx.y, N, K, As, Bs);
}

// merged Q/K/V projection: grid (32, 12); by<8 -> Q, 8..9 -> K, 10..11 -> V (V writes VT directly)
__global__ __launch_bounds__(256) void gemm_qkv(const bf16* __restrict__ qx,
                                                const bf16* __restrict__ kx,
                                                const bf16* __restrict__ vx,
                                                const bf16* __restrict__ wqx,
                                                const bf16* __restrict__ wkx,
                                                const bf16* __restrict__ wvx,
                                                const float* __restrict__ bq,
                                                const float* __restrict__ bk,
                                                const float* __restrict__ bv,
                                                bf16* __restrict__ Qp, bf16* __restrict__ Kp,
                                                bf16* __restrict__ VT) {
    __shared__ bf16 As[4096];
    __shared__ bf16 Bs[4096];
    const int by = blockIdx.y;
    if (by < 8) {
        gemm_body<0>(qx, wqx, bq, Qp, blockIdx.x, by, 1024, 1024, As, Bs);
    } else if (by < 10) {
        gemm_body<0>(kx, wkx, bk, Kp, blockIdx.x, by - 8, 256, 1024, As, Bs);
    } else {
        gemm_body<2>(vx, wvx, bv, VT, blockIdx.x, by - 10, 256, 1024, As, Bs);
    }
}

// ---------------- merged attention (R24, unchanged) ----------------
__global__ __launch_bounds__(512, 4) void attn_all(const bf16* __restrict__ Qp,
                                                   const bf16* __restrict__ Kp,
                                                   const bf16* __restrict__ VT,
                                                   float* __restrict__ attn_out,
                                                   bf16* __restrict__ ctx) {
    __shared__ bf16 KV[4][4096];  // 32 KB: pass A = K ring4; pass B = K{0,1}, V{2,3}
    __shared__ bf16 Pw[8][1024];  // 16 KB: per-wave [16 q][64 k] bf16, XOR-swizzled
    const int raw = blockIdx.x;
    const int wg = (raw & 7) * 64 + (raw >> 3);  // 512 % 8 == 0: bijective
    const int bh = wg >> 4;
    const int qt = wg & 15;
    const int h = bh & (NH - 1), b = bh >> 4, g = h >> 2;
    const int tid = threadIdx.x, wave = tid >> 6, lane = tid & 63;
    const int l15 = lane & 15, lhi = lane >> 4;
    const int qw = qt * 128 + wave * 16;
    const int sw = (l15 & 7) << 4;

    const bf16* qb = Qp + (size_t)(b * S_LEN + qw + l15) * DMODEL + h * DKH + lhi * 8;
    bf16x8 aq0 = *(const bf16x8_a*)qb;
    bf16x8 aq1 = *(const bf16x8_a*)(qb + 32);

    const int srow = tid >> 3;
    const int scc = (tid & 7) ^ (srow & 7);
    const bf16* ksrc = Kp + (size_t)(b * S_LEN + srow) * KVD + g * DKH + scc * 8;
    const bf16* vsrc = VT + ((size_t)(b * NKVH + g) * DKH + srow) * S_LEN + scc * 8;

    // ================= pass A: denominators (K ring-4, depth-2 prefetch) =================
    gll16(ksrc, &KV[0][wave * 512]);
    gll16(ksrc + (size_t)64 * KVD, &KV[1][wave * 512]);
    float lsum = 0.f;
    for (int c = 0; c < 32; ++c) {
        if (c < 30) gll16(ksrc + (size_t)((c + 2) * 64) * KVD, &KV[(c + 2) & 3][wave * 512]);
        if (c < 30) { VWAIT(2); } else if (c == 30) { VWAIT(1); } else { VWAIT(0); }
        __builtin_amdgcn_s_barrier();
        const char* kc = (const char*)&KV[c & 3][0];
        f32x4 a0 = {0.f, 0.f, 0.f, 0.f}, a1 = a0, a2 = a0, a3 = a0;
        __builtin_amdgcn_s_setprio(1);
        {
            const int rb = l15 * 128;
            bf16x8 k0 = *(const bf16x8_a*)(kc + rb + ((lhi * 16) ^ sw));
            bf16x8 k1 = *(const bf16x8_a*)(kc + rb + ((lhi * 16 + 64) ^ sw));
            a0 = __builtin_amdgcn_mfma_f32_16x16x32_bf16(k0, aq0, a0, 0, 0, 0);
            a0 = __builtin_amdgcn_mfma_f32_16x16x32_bf16(k1, aq1, a0, 0, 0, 0);
        }
        {
            const int rb = (16 + l15) * 128;
            bf16x8 k0 = *(const bf16x8_a*)(kc + rb + ((lhi * 16) ^ sw));
            bf16x8 k1 = *(const bf16x8_a*)(kc + rb + ((lhi * 16 + 64) ^ sw));
            a1 = __builtin_amdgcn_mfma_f32_16x16x32_bf16(k0, aq0, a1, 0, 0, 0);
            a1 = __builtin_amdgcn_mfma_f32_16x16x32_bf16(k1, aq1, a1, 0, 0, 0);
        }
        {
            const int rb = (32 + l15) * 128;
            bf16x8 k0 = *(const bf16x8_a*)(kc + rb + ((lhi * 16) ^ sw));
            bf16x8 k1 = *(const bf16x8_a*)(kc + rb + ((lhi * 16 + 64) ^ sw));
            a2 = __builtin_amdgcn_mfma_f32_16x16x32_bf16(k0, aq0, a2, 0, 0, 0);
            a2 = __builtin_amdgcn_mfma_f32_16x16x32_bf16(k1, aq1, a2, 0, 0, 0);
        }
        {
            const int rb = (48 + l15) * 128;
            bf16x8 k0 = *(const bf16x8_a*)(kc + rb + ((lhi * 16) ^ sw));
            bf16x8 k1 = *(const bf16x8_a*)(kc + rb + ((lhi * 16 + 64) ^ sw));
            a3 = __builtin_amdgcn_mfma_f32_16x16x32_bf16(k0, aq0, a3, 0, 0, 0);
            a3 = __builtin_amdgcn_mfma_f32_16x16x32_bf16(k1, aq1, a3, 0, 0, 0);
        }
        __builtin_amdgcn_s_setprio(0);
#pragma unroll
        for (int j = 0; j < 4; ++j)
            lsum += __builtin_exp2f(a0[j] * SCALE_LOG2E) + __builtin_exp2f(a1[j] * SCALE_LOG2E) +
                    __builtin_exp2f(a2[j] * SCALE_LOG2E) + __builtin_exp2f(a3[j] * SCALE_LOG2E);
    }
    lsum += __shfl_xor(lsum, 16, 64);
    lsum += __shfl_xor(lsum, 32, 64);
    const float nlog = -__builtin_log2f(lsum);

    // pass-B prologue staging (KV[0]/KV[2] dead for all waves past the c=31 barrier)
    gll16(ksrc, &KV[0][wave * 512]);
    gll16(vsrc, &KV[2][wave * 512]);

    // ================= pass B: probs + PV (K,V ring-2; P wave-private) =================
    f32x4 cacc[4] = {};
    char* pl = (char*)&Pw[wave][0] + l15 * 128;
    char* pls = (char*)&Pw[wave][0];
    const int stslot = lane & 15;
    const int strow4 = lane >> 4;
    float* gstb = attn_out + ((size_t)bh * S_LEN + qw) * S_LEN;

    for (int c = 0; c < 32; ++c) {
        if (c == 0) { VWAIT(0); } else { VWAIT(4); }
        __builtin_amdgcn_s_barrier();
        if (c < 31) {
            gll16(ksrc + (size_t)((c + 1) * 64) * KVD, &KV[(c + 1) & 1][wave * 512]);
            gll16(vsrc + (c + 1) * 64, &KV[2 + ((c + 1) & 1)][wave * 512]);
            __builtin_amdgcn_sched_barrier(0);
        }
        const char* kc = (const char*)&KV[c & 1][0];
        f32x4 a0 = {0.f, 0.f, 0.f, 0.f}, a1 = a0, a2 = a0, a3 = a0;
        __builtin_amdgcn_s_setprio(1);
        {
            const int rb = l15 * 128;
            bf16x8 k0 = *(const bf16x8_a*)(kc + rb + ((lhi * 16) ^ sw));
            bf16x8 k1 = *(const bf16x8_a*)(kc + rb + ((lhi * 16 + 64) ^ sw));
            a0 = __builtin_amdgcn_mfma_f32_16x16x32_bf16(k0, aq0, a0, 0, 0, 0);
            a0 = __builtin_amdgcn_mfma_f32_16x16x32_bf16(k1, aq1, a0, 0, 0, 0);
        }
        {
            const int rb = (16 + l15) * 128;
            bf16x8 k0 = *(const bf16x8_a*)(kc + rb + ((lhi * 16) ^ sw));
            bf16x8 k1 = *(const bf16x8_a*)(kc + rb + ((lhi * 16 + 64) ^ sw));
            a1 = __builtin_amdgcn_mfma_f32_16x16x32_bf16(k0, aq0, a1, 0, 0, 0);
            a1 = __builtin_amdgcn_mfma_f32_16x16x32_bf16(k1, aq1, a1, 0, 0, 0);
        }
        {
            const int rb = (32 + l15) * 128;
            bf16x8 k0 = *(const bf16x8_a*)(kc + rb + ((lhi * 16) ^ sw));
            bf16x8 k1 = *(const bf16x8_a*)(kc + rb + ((lhi * 16 + 64) ^ sw));
            a2 = __builtin_amdgcn_mfma_f32_16x16x32_bf16(k0, aq0, a2, 0, 0, 0);
            a2 = __builtin_amdgcn_mfma_f32_16x16x32_bf16(k1, aq1, a2, 0, 0, 0);
        }
        {
            const int rb = (48 + l15) * 128;
            bf16x8 k0 = *(const bf16x8_a*)(kc + rb + ((lhi * 16) ^ sw));
            bf16x8 k1 = *(const bf16x8_a*)(kc + rb + ((lhi * 16 + 64) ^ sw));
            a3 = __builtin_amdgcn_mfma_f32_16x16x32_bf16(k0, aq0, a3, 0, 0, 0);
            a3 = __builtin_amdgcn_mfma_f32_16x16x32_bf16(k1, aq1, a3, 0, 0, 0);
        }
        __builtin_amdgcn_s_setprio(0);
        {
            bf16x4 p0, p1, p2, p3;
#pragma unroll
            for (int j = 0; j < 4; ++j) {
                p0[j] = (bf16)__builtin_exp2f(__builtin_fmaf(a0[j], SCALE_LOG2E, nlog));
                p1[j] = (bf16)__builtin_exp2f(__builtin_fmaf(a1[j], SCALE_LOG2E, nlog));
                p2[j] = (bf16)__builtin_exp2f(__builtin_fmaf(a2[j], SCALE_LOG2E, nlog));
                p3[j] = (bf16)__builtin_exp2f(__builtin_fmaf(a3[j], SCALE_LOG2E, nlog));
            }
            *(bf16x4_a*)(pl + ((0 * 32 + lhi * 8) ^ sw)) = p0;
            *(bf16x4_a*)(pl + ((1 * 32 + lhi * 8) ^ sw)) = p1;
            *(bf16x4_a*)(pl + ((2 * 32 + lhi * 8) ^ sw)) = p2;
            *(bf16x4_a*)(pl + ((3 * 32 + lhi * 8) ^ sw)) = p3;
        }
        bf16x8 ap0 = *(const bf16x8_a*)(pl + ((lhi * 16) ^ sw));
        bf16x8 ap1 = *(const bf16x8_a*)(pl + ((lhi * 16 + 64) ^ sw));
        const char* vc = (const char*)&KV[2 + (c & 1)][0];
        __builtin_amdgcn_s_setprio(1);
#pragma unroll
        for (int t = 0; t < 4; ++t) {
            const int vb = (t * 16 + l15) * 128;
            bf16x8 v0 = *(const bf16x8_a*)(vc + vb + ((lhi * 16) ^ sw));
            bf16x8 v1 = *(const bf16x8_a*)(vc + vb + ((lhi * 16 + 64) ^ sw));
            cacc[t] = __builtin_amdgcn_mfma_f32_16x16x32_bf16(ap0, v0, cacc[t], 0, 0, 0);
            cacc[t] = __builtin_amdgcn_mfma_f32_16x16x32_bf16(ap1, v1, cacc[t], 0, 0, 0);
        }
        __builtin_amdgcn_s_setprio(0);
#pragma unroll
        for (int t = 0; t < 4; ++t) {
            const int r = t * 4 + strow4;
            bf16x4 pv4 =
                *(const bf16x4_a*)(pls + r * 128 + ((stslot * 8) ^ ((r & 7) << 4)));
            f32x4 pf4;
#pragma unroll
            for (int j = 0; j < 4; ++j) pf4[j] = (float)pv4[j];
            __builtin_nontemporal_store(
                pf4, (f32x4g*)(gstb + (size_t)r * S_LEN + c * 64 + stslot * 4));
        }
    }
#pragma unroll
    for (int t = 0; t < 4; ++t)
#pragma unroll
        for (int j = 0; j < 4; ++j) {
            int row = qw + lhi * 4 + j;
            __builtin_nontemporal_store(
                (bf16)cacc[t][j],
                &ctx[(size_t)(b * S_LEN + row) * DMODEL + h * DKH + t * 16 + l15]);
        }
}

extern "C" void kernel_launch(void* const* d_in, const int* in_sizes, int n_in,
                              void* d_out, int out_size, void* d_ws, size_t ws_size,
                              hipStream_t stream) {
    const float* query = (const float*)d_in[0];
    const float* key_i = (const float*)d_in[1];
    const float* value = (const float*)d_in[2];
    const float* Wq = (const float*)d_in[3];
    const float* bq = (const float*)d_in[4];
    const float* Wk = (const float*)d_in[5];
    const float* bk = (const float*)d_in[6];
    const float* Wv = (const float*)d_in[7];
    const float* bv = (const float*)d_in[8];
    const float* Wo = (const float*)d_in[9];
    const float* bo = (const float*)d_in[10];

    char* ws = (char*)d_ws;
    bf16* qx = (bf16*)(ws + 0);
    bf16* kx = (bf16*)(ws + ((size_t)8 << 20));
    bf16* vx = (bf16*)(ws + ((size_t)16 << 20));
    bf16* wqx = (bf16*)(ws + ((size_t)32 << 20));
    bf16* wkx = (bf16*)(ws + ((size_t)34 << 20));
    bf16* wvx = (bf16*)(ws + ((size_t)34 << 20) + ((size_t)512 << 10));
    bf16* wox = (bf16*)(ws + ((size_t)35 << 20));
    bf16* Qp = (bf16*)(ws + ((size_t)37 << 20));
    bf16* Kp = (bf16*)(ws + ((size_t)45 << 20));
    bf16* VT = (bf16*)(ws + ((size_t)49 << 20));
    bf16* ctxb = (bf16*)(ws + ((size_t)51 << 20));

    const int BS = 2 * S_LEN;  // 4096 rows

    cast_all<<<dim3(1024, 7), 256, 0, stream>>>(query, key_i, value, Wq, Wo, Wk, Wv, qx, kx,
                                                vx, wqx, wox, wkx, wvx, BS * DMODEL / 4,
                                                DMODEL * DMODEL / 4, KVD * DMODEL / 4);

    gemm_qkv<<<dim3(32, 12), 256, 0, stream>>>(qx, kx, vx, wqx, wkx, wvx, bq, bk, bv, Qp, Kp,
                                               VT);

    float* attn_out = (float*)d_out + (size_t)BS * DMODEL;
    attn_all<<<512, 512, 0, stream>>>(Qp, Kp, VT, attn_out, ctxb);

    gemm_bt<1><<<dim3(32, 8), 256, 0, stream>>>(ctxb, wox, bo, (float*)d_out, BS, DMODEL, DMODEL);
}